// Round 5
// baseline (351993.384 us; speedup 1.0000x reference)
//
#include <hip/hip_runtime.h>
#include <stdint.h>

#define T_STEPS 4096
#define IN_DIM  512
#define H_DIM   2048
#define NBLK    256
#define STH     512

typedef unsigned int uint32;

// ---------------- wave-wide (64-lane) butterfly reduction (f64) ----------------
__device__ __forceinline__ double wredd(double v) {
#pragma unroll
  for (int m = 32; m >= 1; m >>= 1) v += __shfl_xor(v, m, 64);
  return v;
}

// ---------------- device-coherent (agent-scope) load/store ----------------
__device__ __forceinline__ double agloadd(const double* p) {
  return __hip_atomic_load(const_cast<double*>(p), __ATOMIC_RELAXED, __HIP_MEMORY_SCOPE_AGENT);
}
__device__ __forceinline__ void agstored(double* p, double v) {
  __hip_atomic_store(p, v, __ATOMIC_RELAXED, __HIP_MEMORY_SCOPE_AGENT);
}

// ---------------- threefry2x32 (matches jax) ----------------
__device__ __forceinline__ void threefry2x32(uint32 k0, uint32 k1, uint32& x0, uint32& x1) {
  uint32 ks2 = k0 ^ k1 ^ 0x1BD11BDAu;
  x0 += k0; x1 += k1;
#define TF_R(r) { x0 += x1; x1 = (x1 << r) | (x1 >> (32 - r)); x1 ^= x0; }
  TF_R(13) TF_R(15) TF_R(26) TF_R(6)
  x0 += k1;  x1 += ks2 + 1u;
  TF_R(17) TF_R(29) TF_R(16) TF_R(24)
  x0 += ks2; x1 += k0 + 2u;
  TF_R(13) TF_R(15) TF_R(26) TF_R(6)
  x0 += k0;  x1 += k1 + 3u;
  TF_R(17) TF_R(29) TF_R(16) TF_R(24)
  x0 += k1;  x1 += ks2 + 4u;
  TF_R(13) TF_R(15) TF_R(26) TF_R(6)
  x0 += ks2; x1 += k0 + 5u;
#undef TF_R
}

// ---------------- transpose 8 matrices: 5x HxH (U's, alpha, hebb0), 3x INxH ----------------
__global__ void __launch_bounds__(256) transpose_all(
    const float* __restrict__ Uz, const float* __restrict__ Ur,
    const float* __restrict__ Uh, const float* __restrict__ Al,
    const float* __restrict__ Wz, const float* __restrict__ Wr, const float* __restrict__ Wh,
    const float* __restrict__ Hb0,
    float* __restrict__ UZT, float* __restrict__ URT,
    float* __restrict__ UHT, float* __restrict__ AT,
    float* __restrict__ WZT, float* __restrict__ WRT, float* __restrict__ WHT,
    float* __restrict__ HBT) {
  __shared__ float sm[64][65];
  const float* in; float* out; int R, C;   // in[R][C] -> out[C][R]
  switch (blockIdx.z) {
    case 0: in = Uz;  out = UZT; R = H_DIM; C = H_DIM; break;
    case 1: in = Ur;  out = URT; R = H_DIM; C = H_DIM; break;
    case 2: in = Uh;  out = UHT; R = H_DIM; C = H_DIM; break;
    case 3: in = Al;  out = AT;  R = H_DIM; C = H_DIM; break;
    case 4: in = Hb0; out = HBT; R = H_DIM; C = H_DIM; break;
    case 5: in = Wz;  out = WZT; R = IN_DIM; C = H_DIM; break;
    case 6: in = Wr;  out = WRT; R = IN_DIM; C = H_DIM; break;
    default: in = Wh; out = WHT; R = IN_DIM; C = H_DIM; break;
  }
  int r0 = blockIdx.y * 64, c0 = blockIdx.x * 64;
  if (r0 >= R) return;
#pragma unroll
  for (int l = 0; l < 16; ++l) {
    int idx = threadIdx.x + l * 256;
    int r = idx >> 6, c = idx & 63;
    sm[r][c] = in[(size_t)(r0 + r) * C + c0 + c];
  }
  __syncthreads();
#pragma unroll
  for (int l = 0; l < 16; ++l) {
    int idx = threadIdx.x + l * 256;
    int r = idx >> 6, c = idx & 63;
    out[(size_t)(c0 + r) * R + r0 + c] = sm[c][r];
  }
}

// ---------------- device-wide barrier (slot scheme) ----------------
__device__ __forceinline__ void gridbar(uint32* slots, uint32* go, int b, int tid, uint32 phase) {
  __syncthreads();
  if (b == 0) {
    if (tid > 0 && tid < NBLK) {
      while (__hip_atomic_load(&slots[tid * 16], __ATOMIC_ACQUIRE, __HIP_MEMORY_SCOPE_AGENT) < phase) {}
    }
    __syncthreads();
    if (tid == 0) {
      __hip_atomic_store(go, phase, __ATOMIC_RELEASE, __HIP_MEMORY_SCOPE_AGENT);
    }
  } else {
    if (tid == 0) {
      __hip_atomic_store(&slots[b * 16], phase, __ATOMIC_RELEASE, __HIP_MEMORY_SCOPE_AGENT);
      while (__hip_atomic_load(go, __ATOMIC_ACQUIRE, __HIP_MEMORY_SCOPE_AGENT) < phase) {}
    }
  }
  __syncthreads();
}

// ---------------- persistent sequential scan (full f64; hebb f64 in registers) ------
// 256 blocks x 512 threads; block b owns columns [8b, 8b+8), wave w -> column j = 8b+w.
// Each lane holds hebb^T[j][m*64+lane] for m=0..31 in 32 f64 registers.
__global__ void __launch_bounds__(STH, 1) scan_kernel(
    const float* __restrict__ h0, const float* __restrict__ x,
    const float* __restrict__ bz, const float* __restrict__ br, const float* __restrict__ bh,
    const float* __restrict__ eta_p,
    const float* __restrict__ UZT, const float* __restrict__ URT,
    const float* __restrict__ UHT, const float* __restrict__ AT,
    const float* __restrict__ WZT, const float* __restrict__ WRT, const float* __restrict__ WHT,
    float* __restrict__ HBT,     // in: hebb0^T; out: hebb_T^T
    double* __restrict__ Y, double* __restrict__ RH,
    uint32* slots, uint32* go) {
  __shared__ double hbufA[H_DIM];      // 16 KiB  h_t
  __shared__ double hbufB[H_DIM];      // 16 KiB  h_{t-1}
  __shared__ double rhsh[H_DIM];       // 16 KiB  rh
  __shared__ float  xsh[IN_DIM];       // 2 KiB
  const int b = blockIdx.x, tid = threadIdx.x;
  const int w = tid >> 6, lane = tid & 63;
  const int j0 = b * 8, j = j0 + w;
  const double eta = (double)eta_p[0], dec = 1.0 - eta;
  const double bzj = (double)bz[j], brj = (double)br[j], bhj = (double)bh[j];

  // hebb^T column j into registers (coalesced via HBT)
  double hb[32];
  const float* hbtj = HBT + (size_t)j * H_DIM;
#pragma unroll
  for (int m = 0; m < 32; ++m) hb[m] = (double)hbtj[m * 64 + lane];

  const float* uzp = UZT + (size_t)j * H_DIM;
  const float* urp = URT + (size_t)j * H_DIM;
  const float* uhp = UHT + (size_t)j * H_DIM;
  const float* atp = AT  + (size_t)j * H_DIM;
  const float* wzp = WZT + (size_t)j * IN_DIM;
  const float* wrp = WRT + (size_t)j * IN_DIM;
  const float* whp = WHT + (size_t)j * IN_DIM;
  double* hcur = hbufA; double* hprv = hbufB;
  uint32 phase = 0;

  for (int t = 0; t < T_STEPS; ++t) {
    // stage h_t (written by other XCDs last step) and x_t
    if (t == 0) {
      for (int k = tid; k < H_DIM; k += STH) hcur[k] = (double)h0[k];
    } else {
      const double* yp = Y + (size_t)(t - 1) * H_DIM;
      for (int k = tid; k < H_DIM; k += STH) hcur[k] = agloadd(yp + k);
    }
    for (int k = tid; k < IN_DIM; k += STH) xsh[k] = x[(size_t)t * IN_DIM + k];
    __syncthreads();

    // phase 1: fused x-projections + z,r gates (all f64)
    double sz = 0.0, sr = 0.0, sh = 0.0;
#pragma unroll
    for (int m = 0; m < IN_DIM / 64; ++m) {
      int i = m * 64 + lane;
      double xv = (double)xsh[i];
      sz = fma(xv, (double)wzp[i], sz);
      sr = fma(xv, (double)wrp[i], sr);
      sh = fma(xv, (double)whp[i], sh);
    }
#pragma unroll 8
    for (int m = 0; m < H_DIM / 64; ++m) {
      int i = m * 64 + lane;
      double hv = hcur[i];
      sz = fma(hv, (double)uzp[i], sz);
      sr = fma(hv, (double)urp[i], sr);
    }
    sz = wredd(sz); sr = wredd(sr);
    double z = 1.0 / (1.0 + exp(-(sz + bzj)));
    double r = 1.0 / (1.0 + exp(-(sr + brj)));
    double hj = hcur[j];
    if (lane == 0) agstored(&RH[j], r * hj);

    ++phase; gridbar(slots, go, b, tid, phase);   // rh exchange

    for (int k = tid; k < H_DIM; k += STH) rhsh[k] = agloadd(&RH[k]);
    __syncthreads();

    // phase 2: deferred hebb update (f64 regs) fused with (Uh + alpha*hebb) matvec
    double acc = sh;
    if (t == 0) {
#pragma unroll
      for (int m = 0; m < 32; ++m) {
        int i = m * 64 + lane;
        acc = fma(rhsh[i], fma((double)atp[i], hb[m], (double)uhp[i]), acc);
      }
    } else {
      double cj = eta * hj;   // hebb_t = dec*hebb_{t-1} + eta * h_{t-1,i} * h_{t,j}
#pragma unroll
      for (int m = 0; m < 32; ++m) {
        int i = m * 64 + lane;
        double hbv = fma(cj, hprv[i], dec * hb[m]);
        hb[m] = hbv;
        acc = fma(rhsh[i], fma((double)atp[i], hbv, (double)uhp[i]), acc);
      }
    }
    acc = wredd(acc);
    double htl = tanh(acc + bhj);
    double hnew = (1.0 - z) * hj + z * htl;
    if (lane == 0) agstored(&Y[(size_t)t * H_DIM + j], hnew);

    ++phase; gridbar(slots, go, b, tid, phase);   // h exchange

    double* tmp = hcur; hcur = hprv; hprv = tmp;  // h_t -> h_{t-1}
  }

  // finalize: hebb_T = dec*hebb_{T-1} + eta*outer(Y[T-2], Y[T-1]) -> HBT (transposed, coalesced)
  const double* hA = Y + (size_t)(T_STEPS - 2) * H_DIM;
  double hbj = agloadd(Y + (size_t)(T_STEPS - 1) * H_DIM + j);
  float* hbto = HBT + (size_t)j * H_DIM;
#pragma unroll
  for (int m = 0; m < 32; ++m) {
    int i = m * 64 + lane;
    hbto[i] = (float)fma(eta * agloadd(hA + i), hbj, dec * hb[m]);
  }
}

// ---------------- output GEMM (f64) + categorical sampling (partitionable threefry) + hT ----
__global__ void __launch_bounds__(64) outk(
    const double* __restrict__ Y, const float* __restrict__ Wo,
    const float* __restrict__ bo, const int* __restrict__ seedp,
    float* __restrict__ out) {
  int bid = blockIdx.x, lane = threadIdx.x;
  if (bid >= T_STEPS) {  // hT copy blocks
    int jj = (bid - T_STEPS) * 64 + lane;
    out[20480 + jj] = (float)Y[(size_t)(T_STEPS - 1) * H_DIM + jj];
    return;
  }
  int t = bid;
  double a0 = 0., a1 = 0., a2 = 0., a3 = 0.;
  const double* yrow = Y + (size_t)t * H_DIM;
  for (int jj = lane; jj < H_DIM; jj += 64) {
    double yv = yrow[jj];
    float4 wv = ((const float4*)Wo)[jj];
    a0 = fma(yv, (double)wv.x, a0); a1 = fma(yv, (double)wv.y, a1);
    a2 = fma(yv, (double)wv.z, a2); a3 = fma(yv, (double)wv.w, a3);
  }
  a0 = wredd(a0); a1 = wredd(a1); a2 = wredd(a2); a3 = wredd(a3);
  if (lane == 0) {
    double l0 = a0 + (double)bo[0], l1 = a1 + (double)bo[1];
    double l2 = a2 + (double)bo[2], l3 = a3 + (double)bo[3];
    float4 o; o.x = (float)l0; o.y = (float)l1; o.z = (float)l2; o.w = (float)l3;
    ((float4*)out)[t] = o;

    // action = jax.random.categorical(fold_in(key(seed),1), logits[:, :2])
    // partitionable threefry (jax >= 0.4.36 default): bits(n) = x0^x1 of
    // threefry2x32(folded_key, (n>>32, n&0xffffffff)), n = flat index into (T,2)
    long long sv = (long long)seedp[0];
    uint32 k0 = (uint32)(((unsigned long long)sv) >> 32), k1 = (uint32)(sv & 0xffffffffLL);
    uint32 ak0 = 0u, ak1 = 1u;            // threefry_seed(1) as data
    threefry2x32(k0, k1, ak0, ak1);       // folded key
    uint32 p0 = 0u, p1 = (uint32)(2 * t);
    threefry2x32(ak0, ak1, p0, p1);
    uint32 b0 = p0 ^ p1;
    uint32 q0 = 0u, q1 = (uint32)(2 * t + 1);
    threefry2x32(ak0, ak1, q0, q1);
    uint32 b1 = q0 ^ q1;
    const float tiny = 1.1754943508222875e-38f;
    float f0 = __uint_as_float((b0 >> 9) | 0x3f800000u) - 1.0f;
    float f1 = __uint_as_float((b1 >> 9) | 0x3f800000u) - 1.0f;
    float u0 = fmaxf(tiny, fmaf(f0, 1.0f - tiny, tiny));
    float u1 = fmaxf(tiny, fmaf(f1, 1.0f - tiny, tiny));
    float g0 = -logf(-logf(u0));   // gumbel in f32 (bit-matches jax path)
    float g1 = -logf(-logf(u1));
    double s0 = l0 + (double)g0, s1 = l1 + (double)g1;
    out[16384 + t] = (s1 > s0) ? 1.0f : 0.0f;   // ties -> index 0
  }
}

// ---------------- hebb^T -> row-major d_out ----------------
__global__ void __launch_bounds__(256) hebbout_kernel(const float* __restrict__ HBT,
                                                      float* __restrict__ out) {
  __shared__ float sm[64][65];
  int j0 = blockIdx.x * 64, i0 = blockIdx.y * 64;
#pragma unroll
  for (int l = 0; l < 16; ++l) {
    int idx = threadIdx.x + l * 256;
    int r = idx >> 6, c = idx & 63;
    sm[r][c] = HBT[(size_t)(j0 + r) * H_DIM + i0 + c];
  }
  __syncthreads();
#pragma unroll
  for (int l = 0; l < 16; ++l) {
    int idx = threadIdx.x + l * 256;
    int r = idx >> 6, c = idx & 63;
    out[22528 + (size_t)(i0 + r) * H_DIM + j0 + c] = sm[c][r];
  }
}

extern "C" void kernel_launch(void* const* d_in, const int* in_sizes, int n_in,
                              void* d_out, int out_size, void* d_ws, size_t ws_size,
                              hipStream_t stream) {
  (void)in_sizes; (void)n_in; (void)out_size; (void)ws_size;
  const float* x     = (const float*)d_in[0];
  const float* h0    = (const float*)d_in[1];
  const float* hebb0 = (const float*)d_in[2];
  const float* Wz    = (const float*)d_in[3];
  const float* Uz    = (const float*)d_in[4];
  const float* bz    = (const float*)d_in[5];
  const float* Wr    = (const float*)d_in[6];
  const float* Ur    = (const float*)d_in[7];
  const float* br    = (const float*)d_in[8];
  const float* Wh    = (const float*)d_in[9];
  const float* Uh    = (const float*)d_in[10];
  const float* bh    = (const float*)d_in[11];
  const float* alpha = (const float*)d_in[12];
  const float* eta   = (const float*)d_in[13];
  const float* Wo    = (const float*)d_in[14];
  const float* bo    = (const float*)d_in[15];
  const int*   seed  = (const int*)d_in[16];

  const size_t TH = (size_t)T_STEPS * H_DIM;   // 8,388,608
  const size_t HH = (size_t)H_DIM * H_DIM;     // 4,194,304
  const size_t HI = (size_t)H_DIM * IN_DIM;    // 1,048,576
  double* Y  = (double*)d_ws;                  // 64 MB
  double* RH = Y + TH;                         // 16 KB
  float* UZT = (float*)(RH + H_DIM);
  float* URT = UZT + HH;
  float* UHT = URT + HH;
  float* AT  = UHT + HH;
  float* WZT = AT + HH;
  float* WRT = WZT + HI;
  float* WHT = WRT + HI;
  float* HBT = WHT + HI;                       // 16 MB
  uint32* slots = (uint32*)(HBT + HH);
  uint32* go    = slots + NBLK * 16;
  // total ws use: ~157 MB

  hipMemsetAsync(slots, 0, (NBLK * 16 + 16) * sizeof(uint32), stream);
  transpose_all<<<dim3(32, 32, 8), 256, 0, stream>>>(Uz, Ur, Uh, alpha, Wz, Wr, Wh, hebb0,
                                                     UZT, URT, UHT, AT, WZT, WRT, WHT, HBT);
  float* out = (float*)d_out;
  scan_kernel<<<NBLK, STH, 0, stream>>>(h0, x, bz, br, bh, eta,
                                        UZT, URT, UHT, AT, WZT, WRT, WHT,
                                        HBT, Y, RH, slots, go);
  outk<<<T_STEPS + 32, 64, 0, stream>>>(Y, Wo, bo, seed, out);
  hebbout_kernel<<<dim3(32, 32), 256, 0, stream>>>(HBT, out);
}